// Round 25
// baseline (308.587 us; speedup 1.0000x reference)
//
#include <hip/hip_runtime.h>
#include <hip/hip_bf16.h>
#include <math.h>

typedef __attribute__((ext_vector_type(8))) short bf16x8;
typedef __attribute__((ext_vector_type(4))) float f32x4;

__device__ __forceinline__ unsigned f2u(float f) {
    unsigned b = __float_as_uint(f);
    return b ^ ((unsigned)((int)b >> 31) | 0x80000000u);
}
__device__ __forceinline__ float u2f(unsigned u) {
    unsigned b = (u & 0x80000000u) ? (u ^ 0x80000000u) : ~u;
    return __uint_as_float(b);
}
__device__ __forceinline__ unsigned short f2bf(float f) {   // round-to-nearest-even
    unsigned b = __float_as_uint(f);
    return (unsigned short)((b + 0x7FFFu + ((b >> 16) & 1u)) >> 16);
}

// wave-level exact k=16 radix select over 256 values (4 per lane).
__device__ __forceinline__ void radix16(unsigned u0, unsigned u1, unsigned u2, unsigned u3,
                                        unsigned& T, int& kk) {
    unsigned prefix = 0; int k = 16;
    for (int b = 31; b >= 0; --b) {
        unsigned hi = (prefix >> b) | 1u;
        int cnt = __popcll(__ballot((u0 >> b) == hi))
                + __popcll(__ballot((u1 >> b) == hi))
                + __popcll(__ballot((u2 >> b) == hi))
                + __popcll(__ballot((u3 >> b) == hi));
        if (cnt >= k) prefix |= (1u << b); else k -= cnt;
    }
    T = prefix; kk = k;
}

// ---------------- Kernel: f32 -> bf16 conversion (streaming, for x) ----------------
__global__ __launch_bounds__(256) void k_conv(const float* __restrict__ src,
                                              unsigned short* __restrict__ dst, int n8) {
    int tid = blockIdx.x * 256 + threadIdx.x;
    int stride = gridDim.x * 256;
    for (int i = tid; i < n8; i += stride) {
        float4 a = *(const float4*)&src[(size_t)i * 8];
        float4 b = *(const float4*)&src[(size_t)i * 8 + 4];
        uint4 o;
        o.x = (unsigned)f2bf(a.x) | ((unsigned)f2bf(a.y) << 16);
        o.y = (unsigned)f2bf(a.z) | ((unsigned)f2bf(a.w) << 16);
        o.z = (unsigned)f2bf(b.x) | ((unsigned)f2bf(b.y) << 16);
        o.w = (unsigned)f2bf(b.z) | ((unsigned)f2bf(b.w) << 16);
        *(uint4*)&dst[(size_t)i * 8] = o;
    }
}

// ---------------- Kernel K2: fold keys into Wq, output bf16 ----------------
// K2b[p][r = c*2048 + h*256 + k][d] = bf16( sum_dk keys[..] * Wq[..] )
__global__ __launch_bounds__(256) void kK2(const float* __restrict__ keys,
                                           const float* __restrict__ Wq,
                                           unsigned short* __restrict__ K2b) {
    __shared__ float As[16][128];
    __shared__ float Bs[16][128];
    int t  = threadIdx.x;
    int tx = t & 15, ty = t >> 4;
    int p = blockIdx.z;
    int ktile = blockIdx.y & 1, ch = blockIdx.y >> 1;
    int h = ch & 7, c = ch >> 3;
    int m0 = ktile * 128;
    int n0 = blockIdx.x * 128;
    const float* kb = keys + ((size_t)(h * 256 + m0) * 2 + p) * 256;
    const float* wb = Wq + (size_t)(c * 2048 + h * 256) * 512;
    float acc[8][8] = {};
    for (int k0 = 0; k0 < 256; k0 += 16) {
#pragma unroll
        for (int i = 0; i < 2; ++i) {
            int u   = t * 2 + i;
            int row = u >> 2;
            int kc  = (u & 3) << 2;
            float4 av = *(const float4*)&kb[(size_t)row * 512 + k0 + kc];
            As[kc + 0][row] = av.x; As[kc + 1][row] = av.y; As[kc + 2][row] = av.z; As[kc + 3][row] = av.w;
            int v = u;
            int dkrow = v >> 5;
            int dcol  = (v & 31) << 2;
            float4 bv = *(const float4*)&wb[(size_t)(k0 + dkrow) * 512 + n0 + dcol];
            *(float4*)&Bs[dkrow][dcol] = bv;
        }
        __syncthreads();
#pragma unroll
        for (int kk = 0; kk < 16; ++kk) {
            float4 a0 = *(const float4*)&As[kk][ty * 8];
            float4 a1 = *(const float4*)&As[kk][ty * 8 + 4];
            float4 b0 = *(const float4*)&Bs[kk][tx * 4];
            float4 b1 = *(const float4*)&Bs[kk][tx * 4 + 64];
            float a[8] = {a0.x, a0.y, a0.z, a0.w, a1.x, a1.y, a1.z, a1.w};
            float b[8] = {b0.x, b0.y, b0.z, b0.w, b1.x, b1.y, b1.z, b1.w};
#pragma unroll
            for (int i = 0; i < 8; ++i)
#pragma unroll
                for (int j = 0; j < 8; ++j) acc[i][j] += a[i] * b[j];
        }
        __syncthreads();
    }
    unsigned short* Cp = K2b + (size_t)p * 4096 * 512;
#pragma unroll
    for (int i = 0; i < 8; ++i) {
        int r = c * 2048 + h * 256 + m0 + ty * 8 + i;
        uint2 o0, o1;
        o0.x = (unsigned)f2bf(acc[i][0]) | ((unsigned)f2bf(acc[i][1]) << 16);
        o0.y = (unsigned)f2bf(acc[i][2]) | ((unsigned)f2bf(acc[i][3]) << 16);
        o1.x = (unsigned)f2bf(acc[i][4]) | ((unsigned)f2bf(acc[i][5]) << 16);
        o1.y = (unsigned)f2bf(acc[i][6]) | ((unsigned)f2bf(acc[i][7]) << 16);
        *(uint2*)&Cp[(size_t)r * 512 + n0 + tx * 4]      = o0;
        *(uint2*)&Cp[(size_t)r * 512 + n0 + 64 + tx * 4] = o1;
    }
}

// ---------------- Kernel S (MFMA): S[p] = xb[p] @ K2b[p]^T ----------------
__global__ __launch_bounds__(256) void kS_mfma(const unsigned short* __restrict__ xb,
                                               const unsigned short* __restrict__ k2b,
                                               float* __restrict__ S) {
    int t = threadIdx.x;
    int wv = t >> 6, ln = t & 63;
    int p  = blockIdx.z;
    int n0 = blockIdx.y * 128 + wv * 32;
    int e0 = blockIdx.x * 64;
    const unsigned short* A = xb  + (size_t)p * 1024 * 512;
    const unsigned short* B = k2b + (size_t)p * 4096 * 512;
    int lr = ln & 15;
    int lk = (ln >> 4) * 8;

    f32x4 acc00 = {}, acc01 = {}, acc02 = {}, acc03 = {};
    f32x4 acc10 = {}, acc11 = {}, acc12 = {}, acc13 = {};

    for (int k0 = 0; k0 < 512; k0 += 32) {
        bf16x8 a0 = *(const bf16x8*)&A[(size_t)(n0 + lr) * 512 + k0 + lk];
        bf16x8 a1 = *(const bf16x8*)&A[(size_t)(n0 + 16 + lr) * 512 + k0 + lk];
        bf16x8 b0 = *(const bf16x8*)&B[(size_t)(e0 + lr) * 512 + k0 + lk];
        bf16x8 b1 = *(const bf16x8*)&B[(size_t)(e0 + 16 + lr) * 512 + k0 + lk];
        bf16x8 b2 = *(const bf16x8*)&B[(size_t)(e0 + 32 + lr) * 512 + k0 + lk];
        bf16x8 b3 = *(const bf16x8*)&B[(size_t)(e0 + 48 + lr) * 512 + k0 + lk];
        acc00 = __builtin_amdgcn_mfma_f32_16x16x32_bf16(a0, b0, acc00, 0, 0, 0);
        acc01 = __builtin_amdgcn_mfma_f32_16x16x32_bf16(a0, b1, acc01, 0, 0, 0);
        acc02 = __builtin_amdgcn_mfma_f32_16x16x32_bf16(a0, b2, acc02, 0, 0, 0);
        acc03 = __builtin_amdgcn_mfma_f32_16x16x32_bf16(a0, b3, acc03, 0, 0, 0);
        acc10 = __builtin_amdgcn_mfma_f32_16x16x32_bf16(a1, b0, acc10, 0, 0, 0);
        acc11 = __builtin_amdgcn_mfma_f32_16x16x32_bf16(a1, b1, acc11, 0, 0, 0);
        acc12 = __builtin_amdgcn_mfma_f32_16x16x32_bf16(a1, b2, acc12, 0, 0, 0);
        acc13 = __builtin_amdgcn_mfma_f32_16x16x32_bf16(a1, b3, acc13, 0, 0, 0);
    }

    // C/D layout (verified m89): col = lane&15, row = (lane>>4)*4 + reg
    float* C = S + (size_t)p * 1024 * 4096;
    int rbase = (ln >> 4) * 4;
    int cw = ln & 15;
#define STORE_FRAG(ACC, AF, BF)                                                   \
    {                                                                             \
        _Pragma("unroll")                                                         \
        for (int r = 0; r < 4; ++r)                                               \
            C[(size_t)(n0 + (AF)*16 + rbase + r) * 4096 + e0 + (BF)*16 + cw] = ACC[r]; \
    }
    STORE_FRAG(acc00, 0, 0); STORE_FRAG(acc01, 0, 1); STORE_FRAG(acc02, 0, 2); STORE_FRAG(acc03, 0, 3);
    STORE_FRAG(acc10, 1, 0); STORE_FRAG(acc11, 1, 1); STORE_FRAG(acc12, 1, 2); STORE_FRAG(acc13, 1, 3);
#undef STORE_FRAG
}

// ---------------- Kernel topk: radix top16 x2 + combine + top16 + softmax ----------------
__global__ __launch_bounds__(256) void k2_topk(const float* __restrict__ S,
                                               int* __restrict__ widx,
                                               float* __restrict__ wcoef) {
    __shared__ float sx_s[4][2][16];
    __shared__ int   ix_s[4][2][16];

    int t = threadIdx.x;
    int wv = t >> 6, ln = t & 63;
    int task = blockIdx.x * 4 + wv;
    int c = task >> 13;
    int n = (task >> 3) & 1023;
    int h = task & 7;
    unsigned long long lt = (1ull << ln) - 1ull;

    const float* s0p = S + (size_t)n * 4096 + c * 2048 + h * 256 + ln * 4;
    float4 s0 = *(const float4*)&s0p[0];
    float4 s1 = *(const float4*)&s0p[1024UL * 4096];

#define TK_HALF(PIDX, V)                                                          \
    {                                                                             \
        unsigned u0 = f2u(V.x), u1 = f2u(V.y), u2 = f2u(V.z), u3 = f2u(V.w);      \
        unsigned T; int kk;                                                       \
        radix16(u0, u1, u2, u3, T, kk);                                           \
        int base = 0;                                                             \
        { unsigned long long m = __ballot(u0 > T);                                \
          if (u0 > T) { int pos = base + __popcll(m & lt);                        \
              sx_s[wv][PIDX][pos] = V.x; ix_s[wv][PIDX][pos] = ln * 4 + 0; }      \
          base += __popcll(m); }                                                  \
        { unsigned long long m = __ballot(u1 > T);                                \
          if (u1 > T) { int pos = base + __popcll(m & lt);                        \
              sx_s[wv][PIDX][pos] = V.y; ix_s[wv][PIDX][pos] = ln * 4 + 1; }      \
          base += __popcll(m); }                                                  \
        { unsigned long long m = __ballot(u2 > T);                                \
          if (u2 > T) { int pos = base + __popcll(m & lt);                        \
              sx_s[wv][PIDX][pos] = V.z; ix_s[wv][PIDX][pos] = ln * 4 + 2; }      \
          base += __popcll(m); }                                                  \
        { unsigned long long m = __ballot(u3 > T);                                \
          if (u3 > T) { int pos = base + __popcll(m & lt);                        \
              sx_s[wv][PIDX][pos] = V.w; ix_s[wv][PIDX][pos] = ln * 4 + 3; }      \
          base += __popcll(m); }                                                  \
        { unsigned long long m = __ballot(u0 == T); int r = __popcll(m & lt);     \
          if ((u0 == T) && r < kk) { sx_s[wv][PIDX][base + r] = V.x;              \
              ix_s[wv][PIDX][base + r] = ln * 4 + 0; }                            \
          int cn2 = __popcll(m); int tk = cn2 < kk ? cn2 : kk; base += tk; kk -= tk; } \
        { unsigned long long m = __ballot(u1 == T); int r = __popcll(m & lt);     \
          if ((u1 == T) && r < kk) { sx_s[wv][PIDX][base + r] = V.y;              \
              ix_s[wv][PIDX][base + r] = ln * 4 + 1; }                            \
          int cn2 = __popcll(m); int tk = cn2 < kk ? cn2 : kk; base += tk; kk -= tk; } \
        { unsigned long long m = __ballot(u2 == T); int r = __popcll(m & lt);     \
          if ((u2 == T) && r < kk) { sx_s[wv][PIDX][base + r] = V.z;              \
              ix_s[wv][PIDX][base + r] = ln * 4 + 2; }                            \
          int cn2 = __popcll(m); int tk = cn2 < kk ? cn2 : kk; base += tk; kk -= tk; } \
        { unsigned long long m = __ballot(u3 == T); int r = __popcll(m & lt);     \
          if ((u3 == T) && r < kk) { sx_s[wv][PIDX][base + r] = V.w;              \
              ix_s[wv][PIDX][base + r] = ln * 4 + 3; }                            \
          int cn2 = __popcll(m); int tk = cn2 < kk ? cn2 : kk; base += tk; kk -= tk; } \
    }
    TK_HALF(0, s0);
    TK_HALF(1, s1);
#undef TK_HALF
    __syncthreads();

    int t0 = ln, t1 = ln + 64, t2 = ln + 128, t3 = ln + 192;
    float vc0 = sx_s[wv][0][t0 >> 4] + sx_s[wv][1][t0 & 15];
    float vc1 = sx_s[wv][0][t1 >> 4] + sx_s[wv][1][t1 & 15];
    float vc2 = sx_s[wv][0][t2 >> 4] + sx_s[wv][1][t2 & 15];
    float vc3 = sx_s[wv][0][t3 >> 4] + sx_s[wv][1][t3 & 15];
    unsigned u0 = f2u(vc0), u1 = f2u(vc1), u2 = f2u(vc2), u3 = f2u(vc3);
    unsigned T; int kk;
    radix16(u0, u1, u2, u3, T, kk);
    float Tf = u2f(T);

    bool w0 = u0 > T, w1 = u1 > T, w2 = u2 > T, w3 = u3 > T;
    int q0 = 0, q1 = 0, q2 = 0, q3 = 0;
    int base = 0;
    { unsigned long long m = __ballot(w0); q0 = base + __popcll(m & lt); base += __popcll(m); }
    { unsigned long long m = __ballot(w1); q1 = base + __popcll(m & lt); base += __popcll(m); }
    { unsigned long long m = __ballot(w2); q2 = base + __popcll(m & lt); base += __popcll(m); }
    { unsigned long long m = __ballot(w3); q3 = base + __popcll(m & lt); base += __popcll(m); }
#define CMB_EQ(UJ, WJ, QJ) { unsigned long long m = __ballot(UJ == T);          \
    int r = __popcll(m & lt);                                                   \
    if ((UJ == T) && r < kk) { WJ = true; QJ = base + r; }                      \
    int cn2 = __popcll(m); int tk = cn2 < kk ? cn2 : kk;                        \
    base += tk; kk -= tk; }
    CMB_EQ(u0, w0, q0); CMB_EQ(u1, w1, q1); CMB_EQ(u2, w2, q2); CMB_EQ(u3, w3, q3);
#undef CMB_EQ

    float e0 = 0.f, e1 = 0.f, e2 = 0.f, e3 = 0.f;
    int id0 = 0, id1 = 0, id2 = 0, id3 = 0;
    float es = 0.f;
    if (w0) { e0 = __expf(vc0 - Tf); es += e0; id0 = ix_s[wv][0][t0 >> 4] * 256 + ix_s[wv][1][t0 & 15]; }
    if (w1) { e1 = __expf(vc1 - Tf); es += e1; id1 = ix_s[wv][0][t1 >> 4] * 256 + ix_s[wv][1][t1 & 15]; }
    if (w2) { e2 = __expf(vc2 - Tf); es += e2; id2 = ix_s[wv][0][t2 >> 4] * 256 + ix_s[wv][1][t2 & 15]; }
    if (w3) { e3 = __expf(vc3 - Tf); es += e3; id3 = ix_s[wv][0][t3 >> 4] * 256 + ix_s[wv][1][t3 & 15]; }
    for (int s = 1; s < 64; s <<= 1) es += __shfl_xor(es, s);
    float inv = 1.f / es;

    int off = ((c * 1024 + n) * 8 + h) * 16;
    if (w0) { wcoef[off + q0] = e0 * inv; widx[off + q0] = id0; }
    if (w1) { wcoef[off + q1] = e1 * inv; widx[off + q1] = id1; }
    if (w2) { wcoef[off + q2] = e2 * inv; widx[off + q2] = id2; }
    if (w3) { wcoef[off + q3] = e3 * inv; widx[off + q3] = id3; }
}

// ---------------- Kernel 3 (f32, round-10 form): gather, gelu, mix ----------------
// Measured 176-186 us, 520 MB FETCH @ ~3.1 TB/s = the random-gather ceiling
// (confirmed at 1KB and 2KB granules, with partitioning and NT-store attempts).
__global__ __launch_bounds__(256) void k3_experts_f32(const float* __restrict__ x,
                                                      const float* __restrict__ w_down,
                                                      const float* __restrict__ w_up,
                                                      const int* __restrict__ widx,
                                                      const float* __restrict__ wcoef,
                                                      float* __restrict__ out) {
    int bid = blockIdx.x;
    int c = bid >> 10, n = bid & 1023;
    int t = threadIdx.x, wv = t >> 6, ln = t & 63;
    __shared__ float wacc[4][512];

    const float* xrow = &x[(c * 1024 + n) * 512];
    float xr[8], oacc[8];
    {
        float4 xa = *(const float4*)&xrow[ln * 8];
        float4 xb = *(const float4*)&xrow[ln * 8 + 4];
        xr[0] = xa.x; xr[1] = xa.y; xr[2] = xa.z; xr[3] = xa.w;
        xr[4] = xb.x; xr[5] = xb.y; xr[6] = xb.z; xr[7] = xb.w;
    }
#pragma unroll
    for (int j = 0; j < 8; ++j) oacc[j] = 0.f;

    const int base = (c * 1024 + n) * 128;
    for (int e = wv * 32; e < wv * 32 + 32; ++e) {
        int   idx = widx[base + e];
        float wgt = wcoef[base + e];
        const float* dr = &w_down[(long)idx * 512 + ln * 8];
        float4 da = *(const float4*)&dr[0];
        float4 db = *(const float4*)&dr[4];
        float part = da.x * xr[0] + da.y * xr[1] + da.z * xr[2] + da.w * xr[3]
                   + db.x * xr[4] + db.y * xr[5] + db.z * xr[6] + db.w * xr[7];
        for (int s = 1; s < 64; s <<= 1) part += __shfl_xor(part, s);
        float hv = part;
        float coef = 0.5f * hv * (1.f + erff(hv * 0.70710678118654752f)) * wgt;
        const float* ur = &w_up[(long)idx * 512 + ln * 8];
        float4 ua = *(const float4*)&ur[0];
        float4 ub = *(const float4*)&ur[4];
        oacc[0] += coef * ua.x; oacc[1] += coef * ua.y; oacc[2] += coef * ua.z; oacc[3] += coef * ua.w;
        oacc[4] += coef * ub.x; oacc[5] += coef * ub.y; oacc[6] += coef * ub.z; oacc[7] += coef * ub.w;
    }
#pragma unroll
    for (int j = 0; j < 8; ++j) wacc[wv][ln * 8 + j] = oacc[j];
    __syncthreads();

    float* orow = &out[(c * 1024 + n) * 512];
    for (int d = t; d < 512; d += 256)
        orow[d] = wacc[0][d] + wacc[1][d] + wacc[2][d] + wacc[3][d];
}

extern "C" void kernel_launch(void* const* d_in, const int* in_sizes, int n_in,
                              void* d_out, int out_size, void* d_ws, size_t ws_size,
                              hipStream_t stream) {
    const float* x      = (const float*)d_in[0];
    const float* Wq     = (const float*)d_in[1];
    const float* keys   = (const float*)d_in[2];
    const float* w_down = (const float*)d_in[3];
    const float* w_up   = (const float*)d_in[4];
    float* out = (float*)d_out;

    char* ws = (char*)d_ws;
    size_t off = 0;
    float* S     = (float*)(ws + off); off += 2048UL * 4096 * 4;        // 32 MiB
    int*   widx  = (int*)(ws + off);   off += 262144UL * 4;             // 1 MiB
    float* wcoef = (float*)(ws + off); off += 262144UL * 4;             // 1 MiB
    unsigned short* K2b = (unsigned short*)(ws + off); off += 2UL * 4096 * 512 * 2; // 8 MiB
    unsigned short* xb  = (unsigned short*)(ws + off); off += 2048UL * 512 * 2;     // 2 MiB

    k_conv<<<512, 256, 0, stream>>>(x, xb, 2048 * 512 / 8);
    kK2<<<dim3(4, 32, 2), 256, 0, stream>>>(keys, Wq, K2b);
    kS_mfma<<<dim3(64, 8, 2), 256, 0, stream>>>(xb, K2b, S);
    k2_topk<<<4096, 256, 0, stream>>>(S, widx, wcoef);
    k3_experts_f32<<<2048, 256, 0, stream>>>(x, w_down, w_up, widx, wcoef, out);
}

// Round 26
// 292.981 us; speedup vs baseline: 1.0533x; 1.0533x over previous
//
#include <hip/hip_runtime.h>
#include <hip/hip_bf16.h>
#include <math.h>

typedef __attribute__((ext_vector_type(8))) short bf16x8;
typedef __attribute__((ext_vector_type(4))) float f32x4;

__device__ __forceinline__ unsigned f2u(float f) {
    unsigned b = __float_as_uint(f);
    return b ^ ((unsigned)((int)b >> 31) | 0x80000000u);
}
__device__ __forceinline__ float u2f(unsigned u) {
    unsigned b = (u & 0x80000000u) ? (u ^ 0x80000000u) : ~u;
    return __uint_as_float(b);
}
__device__ __forceinline__ unsigned short f2bf(float f) {   // round-to-nearest-even
    unsigned b = __float_as_uint(f);
    return (unsigned short)((b + 0x7FFFu + ((b >> 16) & 1u)) >> 16);
}
__device__ __forceinline__ float bflo(unsigned u) { return __uint_as_float(u << 16); }
__device__ __forceinline__ float bfhi(unsigned u) { return __uint_as_float(u & 0xFFFF0000u); }

// wave-level exact k=16 radix select over 256 values (4 per lane).
__device__ __forceinline__ void radix16(unsigned u0, unsigned u1, unsigned u2, unsigned u3,
                                        unsigned& T, int& kk) {
    unsigned prefix = 0; int k = 16;
    for (int b = 31; b >= 0; --b) {
        unsigned hi = (prefix >> b) | 1u;
        int cnt = __popcll(__ballot((u0 >> b) == hi))
                + __popcll(__ballot((u1 >> b) == hi))
                + __popcll(__ballot((u2 >> b) == hi))
                + __popcll(__ballot((u3 >> b) == hi));
        if (cnt >= k) prefix |= (1u << b); else k -= cnt;
    }
    T = prefix; kk = k;
}

// ---------------- Kernel: f32 -> bf16 conversion (streaming, for x) ----------------
__global__ __launch_bounds__(256) void k_conv(const float* __restrict__ src,
                                              unsigned short* __restrict__ dst, int n8) {
    int tid = blockIdx.x * 256 + threadIdx.x;
    int stride = gridDim.x * 256;
    for (int i = tid; i < n8; i += stride) {
        float4 a = *(const float4*)&src[(size_t)i * 8];
        float4 b = *(const float4*)&src[(size_t)i * 8 + 4];
        uint4 o;
        o.x = (unsigned)f2bf(a.x) | ((unsigned)f2bf(a.y) << 16);
        o.y = (unsigned)f2bf(a.z) | ((unsigned)f2bf(a.w) << 16);
        o.z = (unsigned)f2bf(b.x) | ((unsigned)f2bf(b.y) << 16);
        o.w = (unsigned)f2bf(b.z) | ((unsigned)f2bf(b.w) << 16);
        *(uint4*)&dst[(size_t)i * 8] = o;
    }
}

// ---------------- Kernel: interleaved bf16 expert table (dst-order streaming) ----------------
// wdu[e] = [ bf16(w_down[e]) (512) | bf16(w_up[e]) (512) ]  -> 2 KB per expert.
__global__ __launch_bounds__(256) void k_convi2(const float* __restrict__ wd,
                                                const float* __restrict__ wu,
                                                unsigned short* __restrict__ wdu) {
    const int N8 = 2 * 65536 * 512 / 8;   // 8388608 chunks
    int tid = blockIdx.x * 256 + threadIdx.x;
    int stride = gridDim.x * 256;
    for (int i = tid; i < N8; i += stride) {
        int e   = i >> 7;
        int sub = (i >> 6) & 1;
        int d8  = i & 63;
        const float* s = (sub ? wu : wd) + (size_t)e * 512 + d8 * 8;
        float4 a = *(const float4*)&s[0];
        float4 b = *(const float4*)&s[4];
        uint4 o;
        o.x = (unsigned)f2bf(a.x) | ((unsigned)f2bf(a.y) << 16);
        o.y = (unsigned)f2bf(a.z) | ((unsigned)f2bf(a.w) << 16);
        o.z = (unsigned)f2bf(b.x) | ((unsigned)f2bf(b.y) << 16);
        o.w = (unsigned)f2bf(b.z) | ((unsigned)f2bf(b.w) << 16);
        *(uint4*)&wdu[(size_t)i * 8] = o;
    }
}

// ---------------- Kernel K2: fold keys into Wq, output bf16 ----------------
__global__ __launch_bounds__(256) void kK2(const float* __restrict__ keys,
                                           const float* __restrict__ Wq,
                                           unsigned short* __restrict__ K2b) {
    __shared__ float As[16][128];
    __shared__ float Bs[16][128];
    int t  = threadIdx.x;
    int tx = t & 15, ty = t >> 4;
    int p = blockIdx.z;
    int ktile = blockIdx.y & 1, ch = blockIdx.y >> 1;
    int h = ch & 7, c = ch >> 3;
    int m0 = ktile * 128;
    int n0 = blockIdx.x * 128;
    const float* kb = keys + ((size_t)(h * 256 + m0) * 2 + p) * 256;
    const float* wb = Wq + (size_t)(c * 2048 + h * 256) * 512;
    float acc[8][8] = {};
    for (int k0 = 0; k0 < 256; k0 += 16) {
#pragma unroll
        for (int i = 0; i < 2; ++i) {
            int u   = t * 2 + i;
            int row = u >> 2;
            int kc  = (u & 3) << 2;
            float4 av = *(const float4*)&kb[(size_t)row * 512 + k0 + kc];
            As[kc + 0][row] = av.x; As[kc + 1][row] = av.y; As[kc + 2][row] = av.z; As[kc + 3][row] = av.w;
            int v = u;
            int dkrow = v >> 5;
            int dcol  = (v & 31) << 2;
            float4 bv = *(const float4*)&wb[(size_t)(k0 + dkrow) * 512 + n0 + dcol];
            *(float4*)&Bs[dkrow][dcol] = bv;
        }
        __syncthreads();
#pragma unroll
        for (int kk = 0; kk < 16; ++kk) {
            float4 a0 = *(const float4*)&As[kk][ty * 8];
            float4 a1 = *(const float4*)&As[kk][ty * 8 + 4];
            float4 b0 = *(const float4*)&Bs[kk][tx * 4];
            float4 b1 = *(const float4*)&Bs[kk][tx * 4 + 64];
            float a[8] = {a0.x, a0.y, a0.z, a0.w, a1.x, a1.y, a1.z, a1.w};
            float b[8] = {b0.x, b0.y, b0.z, b0.w, b1.x, b1.y, b1.z, b1.w};
#pragma unroll
            for (int i = 0; i < 8; ++i)
#pragma unroll
                for (int j = 0; j < 8; ++j) acc[i][j] += a[i] * b[j];
        }
        __syncthreads();
    }
    unsigned short* Cp = K2b + (size_t)p * 4096 * 512;
#pragma unroll
    for (int i = 0; i < 8; ++i) {
        int r = c * 2048 + h * 256 + m0 + ty * 8 + i;
        uint2 o0, o1;
        o0.x = (unsigned)f2bf(acc[i][0]) | ((unsigned)f2bf(acc[i][1]) << 16);
        o0.y = (unsigned)f2bf(acc[i][2]) | ((unsigned)f2bf(acc[i][3]) << 16);
        o1.x = (unsigned)f2bf(acc[i][4]) | ((unsigned)f2bf(acc[i][5]) << 16);
        o1.y = (unsigned)f2bf(acc[i][6]) | ((unsigned)f2bf(acc[i][7]) << 16);
        *(uint2*)&Cp[(size_t)r * 512 + n0 + tx * 4]      = o0;
        *(uint2*)&Cp[(size_t)r * 512 + n0 + 64 + tx * 4] = o1;
    }
}

// ---------------- Kernel S (MFMA): S[p] = xb[p] @ K2b[p]^T ----------------
__global__ __launch_bounds__(256) void kS_mfma(const unsigned short* __restrict__ xb,
                                               const unsigned short* __restrict__ k2b,
                                               float* __restrict__ S) {
    int t = threadIdx.x;
    int wv = t >> 6, ln = t & 63;
    int p  = blockIdx.z;
    int n0 = blockIdx.y * 128 + wv * 32;
    int e0 = blockIdx.x * 64;
    const unsigned short* A = xb  + (size_t)p * 1024 * 512;
    const unsigned short* B = k2b + (size_t)p * 4096 * 512;
    int lr = ln & 15;
    int lk = (ln >> 4) * 8;

    f32x4 acc00 = {}, acc01 = {}, acc02 = {}, acc03 = {};
    f32x4 acc10 = {}, acc11 = {}, acc12 = {}, acc13 = {};

    for (int k0 = 0; k0 < 512; k0 += 32) {
        bf16x8 a0 = *(const bf16x8*)&A[(size_t)(n0 + lr) * 512 + k0 + lk];
        bf16x8 a1 = *(const bf16x8*)&A[(size_t)(n0 + 16 + lr) * 512 + k0 + lk];
        bf16x8 b0 = *(const bf16x8*)&B[(size_t)(e0 + lr) * 512 + k0 + lk];
        bf16x8 b1 = *(const bf16x8*)&B[(size_t)(e0 + 16 + lr) * 512 + k0 + lk];
        bf16x8 b2 = *(const bf16x8*)&B[(size_t)(e0 + 32 + lr) * 512 + k0 + lk];
        bf16x8 b3 = *(const bf16x8*)&B[(size_t)(e0 + 48 + lr) * 512 + k0 + lk];
        acc00 = __builtin_amdgcn_mfma_f32_16x16x32_bf16(a0, b0, acc00, 0, 0, 0);
        acc01 = __builtin_amdgcn_mfma_f32_16x16x32_bf16(a0, b1, acc01, 0, 0, 0);
        acc02 = __builtin_amdgcn_mfma_f32_16x16x32_bf16(a0, b2, acc02, 0, 0, 0);
        acc03 = __builtin_amdgcn_mfma_f32_16x16x32_bf16(a0, b3, acc03, 0, 0, 0);
        acc10 = __builtin_amdgcn_mfma_f32_16x16x32_bf16(a1, b0, acc10, 0, 0, 0);
        acc11 = __builtin_amdgcn_mfma_f32_16x16x32_bf16(a1, b1, acc11, 0, 0, 0);
        acc12 = __builtin_amdgcn_mfma_f32_16x16x32_bf16(a1, b2, acc12, 0, 0, 0);
        acc13 = __builtin_amdgcn_mfma_f32_16x16x32_bf16(a1, b3, acc13, 0, 0, 0);
    }

    // C/D layout (verified m89): col = lane&15, row = (lane>>4)*4 + reg
    float* C = S + (size_t)p * 1024 * 4096;
    int rbase = (ln >> 4) * 4;
    int cw = ln & 15;
#define STORE_FRAG(ACC, AF, BF)                                                   \
    {                                                                             \
        _Pragma("unroll")                                                         \
        for (int r = 0; r < 4; ++r)                                               \
            C[(size_t)(n0 + (AF)*16 + rbase + r) * 4096 + e0 + (BF)*16 + cw] = ACC[r]; \
    }
    STORE_FRAG(acc00, 0, 0); STORE_FRAG(acc01, 0, 1); STORE_FRAG(acc02, 0, 2); STORE_FRAG(acc03, 0, 3);
    STORE_FRAG(acc10, 1, 0); STORE_FRAG(acc11, 1, 1); STORE_FRAG(acc12, 1, 2); STORE_FRAG(acc13, 1, 3);
#undef STORE_FRAG
}

// ---------------- Kernel topk: radix top16 x2 + combine + top16 + softmax ----------------
__global__ __launch_bounds__(256) void k2_topk(const float* __restrict__ S,
                                               int* __restrict__ widx,
                                               float* __restrict__ wcoef) {
    __shared__ float sx_s[4][2][16];
    __shared__ int   ix_s[4][2][16];

    int t = threadIdx.x;
    int wv = t >> 6, ln = t & 63;
    int task = blockIdx.x * 4 + wv;
    int c = task >> 13;
    int n = (task >> 3) & 1023;
    int h = task & 7;
    unsigned long long lt = (1ull << ln) - 1ull;

    const float* s0p = S + (size_t)n * 4096 + c * 2048 + h * 256 + ln * 4;
    float4 s0 = *(const float4*)&s0p[0];
    float4 s1 = *(const float4*)&s0p[1024UL * 4096];

#define TK_HALF(PIDX, V)                                                          \
    {                                                                             \
        unsigned u0 = f2u(V.x), u1 = f2u(V.y), u2 = f2u(V.z), u3 = f2u(V.w);      \
        unsigned T; int kk;                                                       \
        radix16(u0, u1, u2, u3, T, kk);                                           \
        int base = 0;                                                             \
        { unsigned long long m = __ballot(u0 > T);                                \
          if (u0 > T) { int pos = base + __popcll(m & lt);                        \
              sx_s[wv][PIDX][pos] = V.x; ix_s[wv][PIDX][pos] = ln * 4 + 0; }      \
          base += __popcll(m); }                                                  \
        { unsigned long long m = __ballot(u1 > T);                                \
          if (u1 > T) { int pos = base + __popcll(m & lt);                        \
              sx_s[wv][PIDX][pos] = V.y; ix_s[wv][PIDX][pos] = ln * 4 + 1; }      \
          base += __popcll(m); }                                                  \
        { unsigned long long m = __ballot(u2 > T);                                \
          if (u2 > T) { int pos = base + __popcll(m & lt);                        \
              sx_s[wv][PIDX][pos] = V.z; ix_s[wv][PIDX][pos] = ln * 4 + 2; }      \
          base += __popcll(m); }                                                  \
        { unsigned long long m = __ballot(u3 > T);                                \
          if (u3 > T) { int pos = base + __popcll(m & lt);                        \
              sx_s[wv][PIDX][pos] = V.w; ix_s[wv][PIDX][pos] = ln * 4 + 3; }      \
          base += __popcll(m); }                                                  \
        { unsigned long long m = __ballot(u0 == T); int r = __popcll(m & lt);     \
          if ((u0 == T) && r < kk) { sx_s[wv][PIDX][base + r] = V.x;              \
              ix_s[wv][PIDX][base + r] = ln * 4 + 0; }                            \
          int cn2 = __popcll(m); int tk = cn2 < kk ? cn2 : kk; base += tk; kk -= tk; } \
        { unsigned long long m = __ballot(u1 == T); int r = __popcll(m & lt);     \
          if ((u1 == T) && r < kk) { sx_s[wv][PIDX][base + r] = V.y;              \
              ix_s[wv][PIDX][base + r] = ln * 4 + 1; }                            \
          int cn2 = __popcll(m); int tk = cn2 < kk ? cn2 : kk; base += tk; kk -= tk; } \
        { unsigned long long m = __ballot(u2 == T); int r = __popcll(m & lt);     \
          if ((u2 == T) && r < kk) { sx_s[wv][PIDX][base + r] = V.z;              \
              ix_s[wv][PIDX][base + r] = ln * 4 + 2; }                            \
          int cn2 = __popcll(m); int tk = cn2 < kk ? cn2 : kk; base += tk; kk -= tk; } \
        { unsigned long long m = __ballot(u3 == T); int r = __popcll(m & lt);     \
          if ((u3 == T) && r < kk) { sx_s[wv][PIDX][base + r] = V.w;              \
              ix_s[wv][PIDX][base + r] = ln * 4 + 3; }                            \
          int cn2 = __popcll(m); int tk = cn2 < kk ? cn2 : kk; base += tk; kk -= tk; } \
    }
    TK_HALF(0, s0);
    TK_HALF(1, s1);
#undef TK_HALF
    __syncthreads();

    int t0 = ln, t1 = ln + 64, t2 = ln + 128, t3 = ln + 192;
    float vc0 = sx_s[wv][0][t0 >> 4] + sx_s[wv][1][t0 & 15];
    float vc1 = sx_s[wv][0][t1 >> 4] + sx_s[wv][1][t1 & 15];
    float vc2 = sx_s[wv][0][t2 >> 4] + sx_s[wv][1][t2 & 15];
    float vc3 = sx_s[wv][0][t3 >> 4] + sx_s[wv][1][t3 & 15];
    unsigned u0 = f2u(vc0), u1 = f2u(vc1), u2 = f2u(vc2), u3 = f2u(vc3);
    unsigned T; int kk;
    radix16(u0, u1, u2, u3, T, kk);
    float Tf = u2f(T);

    bool w0 = u0 > T, w1 = u1 > T, w2 = u2 > T, w3 = u3 > T;
    int q0 = 0, q1 = 0, q2 = 0, q3 = 0;
    int base = 0;
    { unsigned long long m = __ballot(w0); q0 = base + __popcll(m & lt); base += __popcll(m); }
    { unsigned long long m = __ballot(w1); q1 = base + __popcll(m & lt); base += __popcll(m); }
    { unsigned long long m = __ballot(w2); q2 = base + __popcll(m & lt); base += __popcll(m); }
    { unsigned long long m = __ballot(w3); q3 = base + __popcll(m & lt); base += __popcll(m); }
#define CMB_EQ(UJ, WJ, QJ) { unsigned long long m = __ballot(UJ == T);          \
    int r = __popcll(m & lt);                                                   \
    if ((UJ == T) && r < kk) { WJ = true; QJ = base + r; }                      \
    int cn2 = __popcll(m); int tk = cn2 < kk ? cn2 : kk;                        \
    base += tk; kk -= tk; }
    CMB_EQ(u0, w0, q0); CMB_EQ(u1, w1, q1); CMB_EQ(u2, w2, q2); CMB_EQ(u3, w3, q3);
#undef CMB_EQ

    float e0 = 0.f, e1 = 0.f, e2 = 0.f, e3 = 0.f;
    int id0 = 0, id1 = 0, id2 = 0, id3 = 0;
    float es = 0.f;
    if (w0) { e0 = __expf(vc0 - Tf); es += e0; id0 = ix_s[wv][0][t0 >> 4] * 256 + ix_s[wv][1][t0 & 15]; }
    if (w1) { e1 = __expf(vc1 - Tf); es += e1; id1 = ix_s[wv][0][t1 >> 4] * 256 + ix_s[wv][1][t1 & 15]; }
    if (w2) { e2 = __expf(vc2 - Tf); es += e2; id2 = ix_s[wv][0][t2 >> 4] * 256 + ix_s[wv][1][t2 & 15]; }
    if (w3) { e3 = __expf(vc3 - Tf); es += e3; id3 = ix_s[wv][0][t3 >> 4] * 256 + ix_s[wv][1][t3 & 15]; }
    for (int s = 1; s < 64; s <<= 1) es += __shfl_xor(es, s);
    float inv = 1.f / es;

    int off = ((c * 1024 + n) * 8 + h) * 16;
    if (w0) { wcoef[off + q0] = e0 * inv; widx[off + q0] = id0; }
    if (w1) { wcoef[off + q1] = e1 * inv; widx[off + q1] = id1; }
    if (w2) { wcoef[off + q2] = e2 * inv; widx[off + q2] = id2; }
    if (w3) { wcoef[off + q3] = e3 * inv; widx[off + q3] = id3; }
}

// ---------------- Kernel 3 (interleaved bf16 table): gather, gelu, mix ----------------
__global__ __launch_bounds__(256) void k3_experts_bf16(const float* __restrict__ x,
                                                       const unsigned short* __restrict__ wdu,
                                                       const int* __restrict__ widx,
                                                       const float* __restrict__ wcoef,
                                                       float* __restrict__ out) {
    int bid = blockIdx.x;
    int c = bid >> 10, n = bid & 1023;
    int t = threadIdx.x, wv = t >> 6, ln = t & 63;
    __shared__ float wacc[4][512];

    const float* xrow = &x[(c * 1024 + n) * 512];
    float xr[8], oacc[8];
    {
        float4 xa = *(const float4*)&xrow[ln * 8];
        float4 xb = *(const float4*)&xrow[ln * 8 + 4];
        xr[0] = xa.x; xr[1] = xa.y; xr[2] = xa.z; xr[3] = xa.w;
        xr[4] = xb.x; xr[5] = xb.y; xr[6] = xb.z; xr[7] = xb.w;
    }
#pragma unroll
    for (int j = 0; j < 8; ++j) oacc[j] = 0.f;

    const int base = (c * 1024 + n) * 128;
    for (int e = wv * 32; e < wv * 32 + 32; ++e) {
        int   idx = widx[base + e];
        float wgt = wcoef[base + e];
        const unsigned short* row = wdu + (size_t)idx * 1024;
        uint4 dv = *(const uint4*)&row[ln * 8];
        uint4 uv = *(const uint4*)&row[512 + ln * 8];
        float part = bflo(dv.x) * xr[0] + bfhi(dv.x) * xr[1]
                   + bflo(dv.y) * xr[2] + bfhi(dv.y) * xr[3]
                   + bflo(dv.z) * xr[4] + bfhi(dv.z) * xr[5]
                   + bflo(dv.w) * xr[6] + bfhi(dv.w) * xr[7];
        for (int s = 1; s < 64; s <<= 1) part += __shfl_xor(part, s);
        float hv = part;
        float coef = 0.5f * hv * (1.f + erff(hv * 0.70710678118654752f)) * wgt;
        oacc[0] += coef * bflo(uv.x); oacc[1] += coef * bfhi(uv.x);
        oacc[2] += coef * bflo(uv.y); oacc[3] += coef * bfhi(uv.y);
        oacc[4] += coef * bflo(uv.z); oacc[5] += coef * bfhi(uv.z);
        oacc[6] += coef * bflo(uv.w); oacc[7] += coef * bfhi(uv.w);
    }

#pragma unroll
    for (int j = 0; j < 8; ++j) wacc[wv][ln * 8 + j] = oacc[j];
    __syncthreads();

    float* orow = &out[(c * 1024 + n) * 512];
    for (int d = t; d < 512; d += 256)
        orow[d] = wacc[0][d] + wacc[1][d] + wacc[2][d] + wacc[3][d];
}

// ---------------- Kernel 3 (f32 fallback) ----------------
__global__ __launch_bounds__(256) void k3_experts_f32(const float* __restrict__ x,
                                                      const float* __restrict__ w_down,
                                                      const float* __restrict__ w_up,
                                                      const int* __restrict__ widx,
                                                      const float* __restrict__ wcoef,
                                                      float* __restrict__ out) {
    int bid = blockIdx.x;
    int c = bid >> 10, n = bid & 1023;
    int t = threadIdx.x, wv = t >> 6, ln = t & 63;
    __shared__ float wacc[4][512];

    const float* xrow = &x[(c * 1024 + n) * 512];
    float xr[8], oacc[8];
    {
        float4 xa = *(const float4*)&xrow[ln * 8];
        float4 xb = *(const float4*)&xrow[ln * 8 + 4];
        xr[0] = xa.x; xr[1] = xa.y; xr[2] = xa.z; xr[3] = xa.w;
        xr[4] = xb.x; xr[5] = xb.y; xr[6] = xb.z; xr[7] = xb.w;
    }
#pragma unroll
    for (int j = 0; j < 8; ++j) oacc[j] = 0.f;

    const int base = (c * 1024 + n) * 128;
    for (int e = wv * 32; e < wv * 32 + 32; ++e) {
        int   idx = widx[base + e];
        float wgt = wcoef[base + e];
        const float* dr = &w_down[(long)idx * 512 + ln * 8];
        float4 da = *(const float4*)&dr[0];
        float4 db = *(const float4*)&dr[4];
        float part = da.x * xr[0] + da.y * xr[1] + da.z * xr[2] + da.w * xr[3]
                   + db.x * xr[4] + db.y * xr[5] + db.z * xr[6] + db.w * xr[7];
        for (int s = 1; s < 64; s <<= 1) part += __shfl_xor(part, s);
        float hv = part;
        float coef = 0.5f * hv * (1.f + erff(hv * 0.70710678118654752f)) * wgt;
        const float* ur = &w_up[(long)idx * 512 + ln * 8];
        float4 ua = *(const float4*)&ur[0];
        float4 ub = *(const float4*)&ur[4];
        oacc[0] += coef * ua.x; oacc[1] += coef * ua.y; oacc[2] += coef * ua.z; oacc[3] += coef * ua.w;
        oacc[4] += coef * ub.x; oacc[5] += coef * ub.y; oacc[6] += coef * ub.z; oacc[7] += coef * ub.w;
    }
#pragma unroll
    for (int j = 0; j < 8; ++j) wacc[wv][ln * 8 + j] = oacc[j];
    __syncthreads();

    float* orow = &out[(c * 1024 + n) * 512];
    for (int d = t; d < 512; d += 256)
        orow[d] = wacc[0][d] + wacc[1][d] + wacc[2][d] + wacc[3][d];
}

extern "C" void kernel_launch(void* const* d_in, const int* in_sizes, int n_in,
                              void* d_out, int out_size, void* d_ws, size_t ws_size,
                              hipStream_t stream) {
    const float* x      = (const float*)d_in[0];
    const float* Wq     = (const float*)d_in[1];
    const float* keys   = (const float*)d_in[2];
    const float* w_down = (const float*)d_in[3];
    const float* w_up   = (const float*)d_in[4];
    float* out = (float*)d_out;

    char* ws = (char*)d_ws;
    size_t off = 0;
    float* S     = (float*)(ws + off); off += 2048UL * 4096 * 4;        // 32 MiB
    int*   widx  = (int*)(ws + off);   off += 262144UL * 4;             // 1 MiB
    float* wcoef = (float*)(ws + off); off += 262144UL * 4;             // 1 MiB
    unsigned short* K2b = (unsigned short*)(ws + off); off += 2UL * 4096 * 512 * 2; // 8 MiB
    unsigned short* xb  = (unsigned short*)(ws + off); off += 2048UL * 512 * 2;     // 2 MiB
    unsigned short* wdu = (unsigned short*)(ws + off); off += 65536UL * 1024 * 2;   // 128 MiB
    bool use_bf16 = (ws_size >= off);

    k_conv<<<512, 256, 0, stream>>>(x, xb, 2048 * 512 / 8);
    kK2<<<dim3(4, 32, 2), 256, 0, stream>>>(keys, Wq, K2b);
    kS_mfma<<<dim3(64, 8, 2), 256, 0, stream>>>(xb, K2b, S);
    k2_topk<<<4096, 256, 0, stream>>>(S, widx, wcoef);
    if (use_bf16) {
        k_convi2<<<4096, 256, 0, stream>>>(w_down, w_up, wdu);
        k3_experts_bf16<<<2048, 256, 0, stream>>>(x, wdu, widx, wcoef, out);
    } else {
        k3_experts_f32<<<2048, 256, 0, stream>>>(x, w_down, w_up, widx, wcoef, out);
    }
}